// Round 8
// baseline (995.585 us; speedup 1.0000x reference)
//
#include <hip/hip_runtime.h>
#include <math.h>

#define B_   4
#define L_   2048
#define DM_  512
#define H_   8
#define DK_  64
#define DFF_ 2048
#define E_   3
#define U_   40
#define R_   8192
#define SCALE_ 0.125f
#define EPS_ 1e-5f

typedef __bf16 bf16x8 __attribute__((ext_vector_type(8)));
typedef float f32x4 __attribute__((ext_vector_type(4)));

__device__ inline unsigned short f2bf(float x) {
  unsigned int u = __float_as_uint(x);
  unsigned int r = (u + 0x7fffu + ((u >> 16) & 1u)) >> 16;
  return (unsigned short)r;
}

// quad (4-lane) sum via DPP quad_perm — VALU-only, no DS-pipe shuffle.
__device__ inline float qsum4(float p) {
  p += __int_as_float(__builtin_amdgcn_mov_dpp(__float_as_int(p), 0xB1, 0xF, 0xF, true)); // xor 1
  p += __int_as_float(__builtin_amdgcn_mov_dpp(__float_as_int(p), 0x4E, 0xF, 0xF, true)); // xor 2
  return p;
}

// ---------------------------------------------------------------------------
// Weight transpose fp32 [R][C] -> bf16 [C][R].
// ---------------------------------------------------------------------------
__global__ __launch_bounds__(256) void wtrans(
    const float* __restrict__ s0, const float* __restrict__ s1,
    const float* __restrict__ s2, const float* __restrict__ s3,
    unsigned short* __restrict__ dst, int R, int C, int permat) {
  __shared__ float tile[32][33];
  int z = blockIdx.z;
  int which = z / 3, e = z % 3;
  const float* src = (which == 0 ? s0 : which == 1 ? s1 : which == 2 ? s2 : s3);
  src += (size_t)e * permat;
  unsigned short* d = dst + (size_t)z * permat;
  int c0 = blockIdx.x << 5, r0 = blockIdx.y << 5;
  int tx = threadIdx.x & 31, ty = threadIdx.x >> 5;
  for (int rr = ty; rr < 32; rr += 8)
    tile[rr][tx] = src[(size_t)(r0 + rr) * C + c0 + tx];
  __syncthreads();
  for (int cc = ty; cc < 32; cc += 8)
    d[(size_t)(c0 + cc) * R + r0 + tx] = f2bf(tile[tx][cc]);
}

// ---------------------------------------------------------------------------
// x = DNAs @ W_pre + b_pre ; writes fp32 X and bf16 Xbf
// ---------------------------------------------------------------------------
__global__ __launch_bounds__(256) void pre_kernel(
    const float* __restrict__ DNAs, const float* __restrict__ Wp,
    const float* __restrict__ bp, float* __restrict__ X,
    unsigned short* __restrict__ Xbf) {
  int t = blockIdx.x * 256 + threadIdx.x;
  int r = t >> 9, d = t & 511;
  float4 dna = *(const float4*)(DNAs + r * 4);
  float v = dna.x * Wp[d] + dna.y * Wp[512 + d] + dna.z * Wp[1024 + d] +
            dna.w * Wp[1536 + d] + bp[d];
  X[t] = v;
  Xbf[t] = f2bf(v);
}

// ---------------------------------------------------------------------------
// bf16 MFMA GEMM (m97 structure, 128x128 tile, BK=64, XOR-swizzled LDS).
// OUT: 0 = fp32 [M,N]; 1 = fp32 QKV remap (B,H,L,DK); 2 = bf16 + ReLU.
// QKVZ: blockIdx.z selects weight/bias/output (QKV fused launch).
// ---------------------------------------------------------------------------
template <int OUT, bool QKVZ>
__global__ __launch_bounds__(256) void mgemm(
    const unsigned short* __restrict__ A, const unsigned short* __restrict__ BT,
    const float* __restrict__ bias0, const float* __restrict__ bias1,
    const float* __restrict__ bias2, float* __restrict__ Cf,
    unsigned short* __restrict__ Cb, int M, int N, int K) {
  __shared__ unsigned short As[128 * 64];
  __shared__ unsigned short Bs[128 * 64];
  const int t = threadIdx.x, l = t & 63, w = t >> 6;
  const int m0 = blockIdx.y << 7, n0 = blockIdx.x << 7;
  const int wm = w >> 1, wn = w & 1;
  const float* bias = bias0;
  if (QKVZ) {
    int z = blockIdx.z;
    BT += (size_t)z * 3 * 262144;
    bias = (z == 0 ? bias0 : z == 1 ? bias1 : bias2);
    Cf += (size_t)z * 4194304;
  }
  f32x4 acc[4][4] = {};

  const int srow = l >> 3;
  const int gslot = (l & 7) ^ srow;
  for (int k0 = 0; k0 < K; k0 += 64) {
#pragma unroll
    for (int j = 0; j < 4; ++j) {
      int c = (w << 2) + j;
      int row = (c << 3) + srow;
      const unsigned short* ga = A + (size_t)(m0 + row) * K + k0 + gslot * 8;
      const unsigned short* gb = BT + (size_t)(n0 + row) * K + k0 + gslot * 8;
      __builtin_amdgcn_global_load_lds(
          (const __attribute__((address_space(1))) void*)ga,
          (__attribute__((address_space(3))) void*)(As + (c << 9)), 16, 0, 0);
      __builtin_amdgcn_global_load_lds(
          (const __attribute__((address_space(1))) void*)gb,
          (__attribute__((address_space(3))) void*)(Bs + (c << 9)), 16, 0, 0);
    }
    __syncthreads();
#pragma unroll
    for (int ks = 0; ks < 2; ++ks) {
      bf16x8 af[4], bg[4];
      int slot = (ks << 2) + (l >> 4);
#pragma unroll
      for (int i = 0; i < 4; ++i) {
        int ar = (wm << 6) + (i << 4) + (l & 15);
        af[i] = *(const bf16x8*)(As + ar * 64 + (slot ^ (ar & 7)) * 8);
        int br = (wn << 6) + (i << 4) + (l & 15);
        bg[i] = *(const bf16x8*)(Bs + br * 64 + (slot ^ (br & 7)) * 8);
      }
#pragma unroll
      for (int i = 0; i < 4; ++i)
#pragma unroll
        for (int j = 0; j < 4; ++j)
          acc[i][j] = __builtin_amdgcn_mfma_f32_16x16x32_bf16(af[i], bg[j],
                                                              acc[i][j], 0, 0, 0);
    }
    __syncthreads();
  }

#pragma unroll
  for (int i = 0; i < 4; ++i) {
    int rbase = m0 + (wm << 6) + (i << 4) + ((l >> 4) << 2);
#pragma unroll
    for (int j = 0; j < 4; ++j) {
      int col = n0 + (wn << 6) + (j << 4) + (l & 15);
      float bv = bias[col];
#pragma unroll
      for (int r = 0; r < 4; ++r) {
        int row = rbase + r;
        float v = acc[i][j][r] + bv;
        if (OUT == 2) {
          v = fmaxf(v, 0.f);
          Cb[(size_t)row * N + col] = f2bf(v);
        } else if (OUT == 1) {
          int b = row >> 11, ll = row & 2047, h = col >> 6, d = col & 63;
          Cf[((size_t)(((b << 3) + h) << 11) + ll) * 64 + d] = v;
        } else {
          Cf[(size_t)row * N + col] = v;
        }
      }
    }
  }
}

// ---------------------------------------------------------------------------
// Sampled-score M: 16 queries/wave, 4 lanes/query (16 dims each).
// XCD-affinity (bh = blockIdx&31) keeps each head's K panel L2-resident.
// Quad-DPP reduction (VALU-only) removes the DS shuffle latency chain;
// unroll 8 keeps many independent L2 gathers in flight.
// ---------------------------------------------------------------------------
__global__ __launch_bounds__(256) void qk_m_kernel(
    const float* __restrict__ Q, const float* __restrict__ K,
    const int* __restrict__ sidx, float* __restrict__ Mout) {
  int t = threadIdx.x;
  int wave = t >> 6, lane = t & 63;
  int grp = lane >> 2, sub = lane & 3;
  int bh = blockIdx.x & 31;
  int j = blockIdx.x >> 5;
  int item = (bh << 11) + (j << 6) + wave * 16 + grp;
  int l = item & 2047;
  const float4* qp = (const float4*)(Q + (size_t)item * 64 + sub * 16);
  float4 q0 = qp[0], q1 = qp[1], q2 = qp[2], q3 = qp[3];
  const float* Kb = K + (((size_t)bh << 11) << 6) + sub * 16;
  const int* sp = sidx + l * U_;
  float mx = -INFINITY, sm = 0.f;
#pragma unroll 8
  for (int u = 0; u < U_; ++u) {
    int kidx = sp[u];
    const float4* kp = (const float4*)(Kb + ((size_t)kidx << 6));
    float4 k0 = kp[0], k1 = kp[1], k2 = kp[2], k3 = kp[3];
    float p = q0.x * k0.x + q0.y * k0.y + q0.z * k0.z + q0.w * k0.w;
    p = fmaf(q1.x, k1.x, p); p = fmaf(q1.y, k1.y, p);
    p = fmaf(q1.z, k1.z, p); p = fmaf(q1.w, k1.w, p);
    p = fmaf(q2.x, k2.x, p); p = fmaf(q2.y, k2.y, p);
    p = fmaf(q2.z, k2.z, p); p = fmaf(q2.w, k2.w, p);
    p = fmaf(q3.x, k3.x, p); p = fmaf(q3.y, k3.y, p);
    p = fmaf(q3.z, k3.z, p); p = fmaf(q3.w, k3.w, p);
    p = qsum4(p);
    mx = fmaxf(mx, p);
    sm += p;
  }
  if (sub == 0) Mout[item] = mx - sm * (1.0f / U_);
}

// ---------------------------------------------------------------------------
// Exact top-40 via 4-pass radix select — fully parallel (no serial tails).
// ---------------------------------------------------------------------------
__global__ __launch_bounds__(256) void topk_kernel(
    const float* __restrict__ Mb, int* __restrict__ TOP) {
  __shared__ unsigned vals[2048];
  __shared__ int hist[256];
  __shared__ int suf[256];
  __shared__ unsigned s_prefix;
  __shared__ int s_want, s_cnt, s_run;
  __shared__ int wcnt[4];
  int bh = blockIdx.x, t = threadIdx.x;
  int lane = t & 63, w = t >> 6;
  for (int i = t; i < 2048; i += 256) {
    unsigned u = __float_as_uint(Mb[bh * 2048 + i]);
    vals[i] = (u & 0x80000000u) ? ~u : (u | 0x80000000u);
  }
  if (t == 0) { s_prefix = 0; s_want = U_; s_cnt = 0; s_run = 0; }
  __syncthreads();
#pragma unroll
  for (int shift = 24; shift >= 0; shift -= 8) {
    unsigned pref = s_prefix;
    int want = s_want;
    unsigned hmask = (shift == 24) ? 0u : (0xFFFFFFFFu << (shift + 8));
    hist[t] = 0;
    __syncthreads();
    for (int i = t; i < 2048; i += 256) {
      unsigned v = vals[i];
      if ((v & hmask) == pref) atomicAdd(&hist[(v >> shift) & 255], 1);
    }
    __syncthreads();
    suf[t] = hist[t];
    __syncthreads();
    for (int off = 1; off < 256; off <<= 1) {
      int add = (t + off < 256) ? suf[t + off] : 0;
      __syncthreads();
      suf[t] += add;
      __syncthreads();
    }
    int cgt = (t == 255) ? 0 : suf[t + 1];
    if (suf[t] >= want && cgt < want) {
      s_prefix = pref | ((unsigned)t << shift);
      s_want = want - cgt;
    }
    __syncthreads();
  }
  unsigned T = s_prefix;
  int want_eq = s_want;
  int base = U_ - want_eq;
  for (int i = t; i < 2048; i += 256) {
    if (vals[i] > T) {
      int slot = atomicAdd(&s_cnt, 1);
      TOP[bh * U_ + slot] = i;
    }
  }
  for (int c = 0; c < 8; ++c) {
    int i = (c << 8) + t;
    bool eq = (vals[i] == T);
    unsigned long long m = __ballot(eq);
    if (lane == 0) wcnt[w] = __popcll(m);
    __syncthreads();
    int woff = 0;
    for (int ww = 0; ww < w; ++ww) woff += wcnt[ww];
    if (eq) {
      int rank = s_run + woff + __popcll(m & ((1ull << lane) - 1ull));
      if (rank < want_eq) TOP[bh * U_ + base + rank] = i;
    }
    __syncthreads();
    if (t == 0) s_run += wcnt[0] + wcnt[1] + wcnt[2] + wcnt[3];
    __syncthreads();
  }
}

// ---------------------------------------------------------------------------
// vmean[bh,d] = mean over L of V[bh,l,d]; also bf16 copy for ctxfill.
// ---------------------------------------------------------------------------
__global__ __launch_bounds__(256) void vmean_kernel(
    const float* __restrict__ V, float* __restrict__ VM,
    unsigned short* __restrict__ VMbf) {
  __shared__ float p[4][64];
  int bh = blockIdx.x;
  int d = threadIdx.x & 63, c = threadIdx.x >> 6;
  const float* Vb = V + (((size_t)bh << 11) + c * 512) * 64;
  float s = 0.f;
  for (int l = 0; l < 512; ++l) s += Vb[l * 64 + d];
  p[c][d] = s;
  __syncthreads();
  if (threadIdx.x < 64) {
    float m = (p[0][d] + p[1][d] + p[2][d] + p[3][d]) * (1.0f / 2048.0f);
    VM[bh * 64 + d] = m;
    VMbf[bh * 64 + d] = f2bf(m);
  }
}

// ---------------------------------------------------------------------------
// S[bh,u,k] = scale * dot(Q[top[bh,u]], K[bh,k]).
// ---------------------------------------------------------------------------
__global__ __launch_bounds__(256) void attn_score(
    const float* __restrict__ Q, const float* __restrict__ K,
    const int* __restrict__ TOP, float* __restrict__ S) {
  __shared__ float Ks[128 * 65];
  __shared__ float Qs[40 * 64];
  int bh = blockIdx.y, k0 = blockIdx.x << 7;
  int t = threadIdx.x;
  for (int i = t; i < 2560; i += 256) {
    int u = i >> 6, d = i & 63;
    int row = TOP[bh * U_ + u];
    Qs[i] = Q[(((size_t)bh << 11) + row) * 64 + d];
  }
  for (int i = t; i < 8192; i += 256) {
    int k = i >> 6, d = i & 63;
    Ks[k * 65 + d] = K[(((size_t)bh << 11) + k0 + k) * 64 + d];
  }
  __syncthreads();
  int kk = t & 127, ug = (t >> 7) * 20;
  const float* kp = Ks + kk * 65;
  for (int u = ug; u < ug + 20; ++u) {
    const float* qp = Qs + u * 64;
    float s = 0.f;
#pragma unroll 8
    for (int d = 0; d < 64; ++d) s = fmaf(qp[d], kp[d], s);
    S[((size_t)bh * U_ + u) * 2048 + k0 + kk] = s * SCALE_;
  }
}

// ---------------------------------------------------------------------------
// softmax + P@V for 8 query-rows per block; V chunk staged once in LDS.
// Writes scattered bf16 rows DIRECTLY into CTX (fused scatter).
// ---------------------------------------------------------------------------
__global__ __launch_bounds__(256) void attn_pv(
    const float* __restrict__ S, const float* __restrict__ V,
    const int* __restrict__ TOP, unsigned short* __restrict__ CTX) {
  __shared__ float Vs[128][64];
  __shared__ float ps[8][128];
  __shared__ float mred[8], ired[8];
  int ug = blockIdx.x, bh = blockIdx.y;
  int t = threadIdx.x, lane = t & 63, w = t >> 6;
  int rowbase = bh * U_ + ug * 8;

  for (int rr = w; rr < 8; rr += 4) {
    const float* Sr = S + (size_t)(rowbase + rr) * 2048;
    float mx = -INFINITY;
    for (int j = 0; j < 32; ++j) mx = fmaxf(mx, Sr[j * 64 + lane]);
#pragma unroll
    for (int s = 32; s; s >>= 1) mx = fmaxf(mx, __shfl_xor(mx, s));
    float sm = 0.f;
    for (int j = 0; j < 32; ++j) sm += __expf(Sr[j * 64 + lane] - mx);
#pragma unroll
    for (int s = 32; s; s >>= 1) sm += __shfl_xor(sm, s);
    if (lane == 0) { mred[rr] = mx; ired[rr] = 1.0f / sm; }
  }
  __syncthreads();

  const float* Vb = V + (((size_t)bh << 11) << 6);
  float acc0 = 0.f, acc1 = 0.f;
  for (int c = 0; c < 16; ++c) {
    int k0 = c << 7;
#pragma unroll
    for (int i = 0; i < 8; ++i) {
      int ve = t + i * 256;
      int k = ve >> 4, dq = ve & 15;
      *(float4*)&Vs[k][dq << 2] = *(const float4*)(Vb + (size_t)(k0 + k) * 64 + (dq << 2));
    }
#pragma unroll
    for (int i = 0; i < 4; ++i) {
      int e = t + i * 256;
      int r = e >> 7, kk = e & 127;
      ps[r][kk] = __expf(S[(size_t)(rowbase + r) * 2048 + k0 + kk] - mred[r]);
    }
    __syncthreads();
    const float* p0 = ps[w];
    const float* p1 = ps[w + 4];
    for (int kk = 0; kk < 128; ++kk) {
      float vv = Vs[kk][lane];
      acc0 = fmaf(p0[kk], vv, acc0);
      acc1 = fmaf(p1[kk], vv, acc1);
    }
    __syncthreads();
  }
  int b = bh >> 3, h = bh & 7;
  int row0 = TOP[rowbase + w];
  int row1 = TOP[rowbase + w + 4];
  CTX[((size_t)((b << 11) + row0) << 9) + (h << 6) + lane] = f2bf(acc0 * ired[w]);
  CTX[((size_t)((b << 11) + row1) << 9) + (h << 6) + lane] = f2bf(acc1 * ired[w + 4]);
}

// ---------------------------------------------------------------------------
// ctx fill (vectorized: 8 bf16 per thread; 2048 blocks x 256 x 8 = 4194304)
// ---------------------------------------------------------------------------
__global__ __launch_bounds__(256) void ctxfill_kernel(
    const unsigned short* __restrict__ VMbf, unsigned short* __restrict__ CTX) {
  int t8 = (blockIdx.x * 256 + threadIdx.x) << 3;
  int c0 = t8 & 511;
  int b = t8 >> 20;
  *(uint4*)(CTX + t8) = *(const uint4*)(VMbf + (b << 9) + c0);
}

// ---------------------------------------------------------------------------
// LayerNorm(512) with optional residual; float2-vectorized.
// ---------------------------------------------------------------------------
template <bool ADD, bool WB>
__global__ __launch_bounds__(256) void ln_kernel(
    const float* __restrict__ Xin, const float* __restrict__ Tin,
    const float* __restrict__ g, const float* __restrict__ bta,
    float* __restrict__ Xout, unsigned short* __restrict__ Xbf) {
  __shared__ float red[8];
  int r = blockIdx.x, t = threadIdx.x;
  int i0 = (r << 9) + (t << 1);
  float2 v = *(const float2*)(Xin + i0);
  if constexpr (ADD) {
    float2 tv = *(const float2*)(Tin + i0);
    v.x += tv.x; v.y += tv.y;
  }
  float sm = v.x + v.y;
#pragma unroll
  for (int s = 32; s; s >>= 1) sm += __shfl_xor(sm, s);
  int lane = t & 63, w = t >> 6;
  if (lane == 0) red[w] = sm;
  __syncthreads();
  float mean = (red[0] + red[1] + red[2] + red[3]) * (1.0f / 512.0f);
  float d0 = v.x - mean, d1 = v.y - mean;
  float sq = d0 * d0 + d1 * d1;
#pragma unroll
  for (int s = 32; s; s >>= 1) sq += __shfl_xor(sq, s);
  if (lane == 0) red[4 + w] = sq;
  __syncthreads();
  float var = (red[4] + red[5] + red[6] + red[7]) * (1.0f / 512.0f);
  float rstd = rsqrtf(var + EPS_);
  float2 gv = *(const float2*)(g + (t << 1));
  float2 bv = *(const float2*)(bta + (t << 1));
  float o0 = d0 * rstd * gv.x + bv.x;
  float o1 = d1 * rstd * gv.y + bv.y;
  *(float2*)(Xout + i0) = make_float2(o0, o1);
  if constexpr (WB) {
    *(unsigned*)(Xbf + i0) = (unsigned)f2bf(o0) | ((unsigned)f2bf(o1) << 16);
  }
}

// ---------------------------------------------------------------------------
// out = softmax(X @ W_out + b_out); one wave per row.
// ---------------------------------------------------------------------------
__global__ __launch_bounds__(256) void out_kernel(
    const float* __restrict__ X, const float* __restrict__ Wout,
    const float* __restrict__ bout, float* __restrict__ out) {
  int w = threadIdx.x >> 6, lane = threadIdx.x & 63;
  int r = blockIdx.x * 4 + w;
  float p0 = 0.f, p1 = 0.f, p2 = 0.f;
  for (int d = lane; d < 512; d += 64) {
    float x = X[(r << 9) + d];
    p0 += x * Wout[d * 3 + 0];
    p1 += x * Wout[d * 3 + 1];
    p2 += x * Wout[d * 3 + 2];
  }
#pragma unroll
  for (int s = 32; s; s >>= 1) {
    p0 += __shfl_xor(p0, s);
    p1 += __shfl_xor(p1, s);
    p2 += __shfl_xor(p2, s);
  }
  if (lane == 0) {
    p0 += bout[0]; p1 += bout[1]; p2 += bout[2];
    float m = fmaxf(p0, fmaxf(p1, p2));
    float e0 = __expf(p0 - m), e1 = __expf(p1 - m), e2 = __expf(p2 - m);
    float z = 1.0f / (e0 + e1 + e2);
    out[r * 3 + 0] = e0 * z;
    out[r * 3 + 1] = e1 * z;
    out[r * 3 + 2] = e2 * z;
  }
}

// ---------------------------------------------------------------------------
extern "C" void kernel_launch(void* const* d_in, const int* in_sizes, int n_in,
                              void* d_out, int out_size, void* d_ws, size_t ws_size,
                              hipStream_t stream) {
  const float* DNAs  = (const float*)d_in[0];
  const float* W_pre = (const float*)d_in[1];
  const float* b_pre = (const float*)d_in[2];
  const float* Wq    = (const float*)d_in[3];
  const float* bq    = (const float*)d_in[4];
  const float* Wk    = (const float*)d_in[5];
  const float* bk    = (const float*)d_in[6];
  const float* Wv    = (const float*)d_in[7];
  const float* bv    = (const float*)d_in[8];
  const float* Wo    = (const float*)d_in[9];
  const float* bo    = (const float*)d_in[10];
  const float* ln1_g = (const float*)d_in[11];
  const float* ln1_b = (const float*)d_in[12];
  const float* W1    = (const float*)d_in[13];
  const float* b1    = (const float*)d_in[14];
  const float* W2    = (const float*)d_in[15];
  const float* b2    = (const float*)d_in[16];
  const float* ln2_g = (const float*)d_in[17];
  const float* ln2_b = (const float*)d_in[18];
  const float* lnf_g = (const float*)d_in[19];
  const float* lnf_b = (const float*)d_in[20];
  const float* W_out = (const float*)d_in[21];
  const float* b_out = (const float*)d_in[22];
  const int*   sidx  = (const int*)d_in[23];
  float* out = (float*)d_out;

  float* ws = (float*)d_ws;
  float*          X     = ws;
  unsigned short* Xbf   = (unsigned short*)(ws + 4194304);
  float*          Qb    = ws + 6291456;
  float*          T     = Qb;
  float*          Kb    = ws + 10485760;
  float*          Vb    = ws + 14680064;
  float*          S     = ws + 18874368;
  unsigned short* CTXbf = (unsigned short*)(ws + 18874368 + 3276800);
  unsigned short* HBbf  = (unsigned short*)(ws + 18874368);
  unsigned short* WT    = (unsigned short*)(ws + 27262976);
  float*          Mb    = ws + 31981568;
  float*          VM    = ws + 32129024;
  int*            TOP   = (int*)(ws + 32131072);
  unsigned short* VMbf  = (unsigned short*)(ws + 32132352);
  unsigned short* WTqkvo = WT;
  unsigned short* WT1    = WT + 3145728;
  unsigned short* WT2    = WT + 6291456;
  (void)in_sizes; (void)n_in; (void)out_size; (void)ws_size;

  wtrans<<<dim3(16, 16, 12), 256, 0, stream>>>(Wq, Wk, Wv, Wo, WTqkvo, 512, 512, 262144);
  wtrans<<<dim3(64, 16, 3), 256, 0, stream>>>(W1, nullptr, nullptr, nullptr, WT1, 512, 2048, 1048576);
  wtrans<<<dim3(16, 64, 3), 256, 0, stream>>>(W2, nullptr, nullptr, nullptr, WT2, 2048, 512, 1048576);

  pre_kernel<<<16384, 256, 0, stream>>>(DNAs, W_pre, b_pre, X, Xbf);

  for (int i = 0; i < E_; ++i) {
    const int bOff = i * DM_;
    mgemm<1, true><<<dim3(4, 64, 3), 256, 0, stream>>>(
        Xbf, WTqkvo + (size_t)i * 262144, bq + bOff, bk + bOff, bv + bOff,
        Qb, nullptr, R_, DM_, DM_);

    qk_m_kernel<<<1024, 256, 0, stream>>>(Qb, Kb, sidx, Mb);
    topk_kernel<<<32, 256, 0, stream>>>(Mb, TOP);
    vmean_kernel<<<32, 256, 0, stream>>>(Vb, VM, VMbf);
    attn_score<<<dim3(16, 32), 256, 0, stream>>>(Qb, Kb, TOP, S);
    ctxfill_kernel<<<2048, 256, 0, stream>>>(VMbf, CTXbf);
    attn_pv<<<dim3(5, 32), 256, 0, stream>>>(S, Vb, TOP, CTXbf);

    mgemm<0, false><<<dim3(4, 64), 256, 0, stream>>>(
        CTXbf, WTqkvo + (size_t)(9 + i) * 262144, bo + bOff, nullptr, nullptr,
        T, nullptr, R_, DM_, DM_);
    ln_kernel<true, true><<<8192, 256, 0, stream>>>(X, T, ln1_g + bOff, ln1_b + bOff, X, Xbf);

    mgemm<2, false><<<dim3(16, 64), 256, 0, stream>>>(
        Xbf, WT1 + (size_t)i * 1048576, b1 + i * DFF_, nullptr, nullptr,
        nullptr, HBbf, R_, DFF_, DM_);
    mgemm<0, false><<<dim3(4, 64), 256, 0, stream>>>(
        HBbf, WT2 + (size_t)i * 1048576, b2 + bOff, nullptr, nullptr,
        T, nullptr, R_, DM_, DFF_);
    ln_kernel<true, true><<<8192, 256, 0, stream>>>(X, T, ln2_g + bOff, ln2_b + bOff, X, Xbf);
  }

  ln_kernel<false, false><<<8192, 256, 0, stream>>>(X, nullptr, lnf_g, lnf_b, X, nullptr);
  out_kernel<<<2048, 256, 0, stream>>>(X, W_out, b_out, out);
}

// Round 9
// 834.805 us; speedup vs baseline: 1.1926x; 1.1926x over previous
//
#include <hip/hip_runtime.h>
#include <math.h>

#define B_   4
#define L_   2048
#define DM_  512
#define H_   8
#define DK_  64
#define DFF_ 2048
#define E_   3
#define U_   40
#define R_   8192
#define SCALE_ 0.125f
#define EPS_ 1e-5f

typedef __bf16 bf16x8 __attribute__((ext_vector_type(8)));
typedef float f32x4 __attribute__((ext_vector_type(4)));

__device__ inline unsigned short f2bf(float x) {
  unsigned int u = __float_as_uint(x);
  unsigned int r = (u + 0x7fffu + ((u >> 16) & 1u)) >> 16;
  return (unsigned short)r;
}

// ---------------------------------------------------------------------------
// Weight transpose fp32 [R][C] -> bf16 [C][R].
// ---------------------------------------------------------------------------
__global__ __launch_bounds__(256) void wtrans(
    const float* __restrict__ s0, const float* __restrict__ s1,
    const float* __restrict__ s2, const float* __restrict__ s3,
    unsigned short* __restrict__ dst, int R, int C, int permat) {
  __shared__ float tile[32][33];
  int z = blockIdx.z;
  int which = z / 3, e = z % 3;
  const float* src = (which == 0 ? s0 : which == 1 ? s1 : which == 2 ? s2 : s3);
  src += (size_t)e * permat;
  unsigned short* d = dst + (size_t)z * permat;
  int c0 = blockIdx.x << 5, r0 = blockIdx.y << 5;
  int tx = threadIdx.x & 31, ty = threadIdx.x >> 5;
  for (int rr = ty; rr < 32; rr += 8)
    tile[rr][tx] = src[(size_t)(r0 + rr) * C + c0 + tx];
  __syncthreads();
  for (int cc = ty; cc < 32; cc += 8)
    d[(size_t)(c0 + cc) * R + r0 + tx] = f2bf(tile[tx][cc]);
}

// ---------------------------------------------------------------------------
// x = DNAs @ W_pre + b_pre ; writes fp32 X and bf16 Xbf
// ---------------------------------------------------------------------------
__global__ __launch_bounds__(256) void pre_kernel(
    const float* __restrict__ DNAs, const float* __restrict__ Wp,
    const float* __restrict__ bp, float* __restrict__ X,
    unsigned short* __restrict__ Xbf) {
  int t = blockIdx.x * 256 + threadIdx.x;
  int r = t >> 9, d = t & 511;
  float4 dna = *(const float4*)(DNAs + r * 4);
  float v = dna.x * Wp[d] + dna.y * Wp[512 + d] + dna.z * Wp[1024 + d] +
            dna.w * Wp[1536 + d] + bp[d];
  X[t] = v;
  Xbf[t] = f2bf(v);
}

// ---------------------------------------------------------------------------
// bf16 MFMA GEMM (m97 structure, 128x128 tile, BK=64, XOR-swizzled LDS).
// OUT: 0 = fp32 [M,N]; 1 = fp32 QKV remap (B,H,L,DK); 2 = bf16 + ReLU.
// QKVZ: blockIdx.z selects weight/bias/output (QKV fused launch).
// ---------------------------------------------------------------------------
template <int OUT, bool QKVZ>
__global__ __launch_bounds__(256) void mgemm(
    const unsigned short* __restrict__ A, const unsigned short* __restrict__ BT,
    const float* __restrict__ bias0, const float* __restrict__ bias1,
    const float* __restrict__ bias2, float* __restrict__ Cf,
    unsigned short* __restrict__ Cb, int M, int N, int K) {
  __shared__ unsigned short As[128 * 64];
  __shared__ unsigned short Bs[128 * 64];
  const int t = threadIdx.x, l = t & 63, w = t >> 6;
  const int m0 = blockIdx.y << 7, n0 = blockIdx.x << 7;
  const int wm = w >> 1, wn = w & 1;
  const float* bias = bias0;
  if (QKVZ) {
    int z = blockIdx.z;
    BT += (size_t)z * 3 * 262144;
    bias = (z == 0 ? bias0 : z == 1 ? bias1 : bias2);
    Cf += (size_t)z * 4194304;
  }
  f32x4 acc[4][4] = {};

  const int srow = l >> 3;
  const int gslot = (l & 7) ^ srow;
  for (int k0 = 0; k0 < K; k0 += 64) {
#pragma unroll
    for (int j = 0; j < 4; ++j) {
      int c = (w << 2) + j;
      int row = (c << 3) + srow;
      const unsigned short* ga = A + (size_t)(m0 + row) * K + k0 + gslot * 8;
      const unsigned short* gb = BT + (size_t)(n0 + row) * K + k0 + gslot * 8;
      __builtin_amdgcn_global_load_lds(
          (const __attribute__((address_space(1))) void*)ga,
          (__attribute__((address_space(3))) void*)(As + (c << 9)), 16, 0, 0);
      __builtin_amdgcn_global_load_lds(
          (const __attribute__((address_space(1))) void*)gb,
          (__attribute__((address_space(3))) void*)(Bs + (c << 9)), 16, 0, 0);
    }
    __syncthreads();
#pragma unroll
    for (int ks = 0; ks < 2; ++ks) {
      bf16x8 af[4], bg[4];
      int slot = (ks << 2) + (l >> 4);
#pragma unroll
      for (int i = 0; i < 4; ++i) {
        int ar = (wm << 6) + (i << 4) + (l & 15);
        af[i] = *(const bf16x8*)(As + ar * 64 + (slot ^ (ar & 7)) * 8);
        int br = (wn << 6) + (i << 4) + (l & 15);
        bg[i] = *(const bf16x8*)(Bs + br * 64 + (slot ^ (br & 7)) * 8);
      }
#pragma unroll
      for (int i = 0; i < 4; ++i)
#pragma unroll
        for (int j = 0; j < 4; ++j)
          acc[i][j] = __builtin_amdgcn_mfma_f32_16x16x32_bf16(af[i], bg[j],
                                                              acc[i][j], 0, 0, 0);
    }
    __syncthreads();
  }

#pragma unroll
  for (int i = 0; i < 4; ++i) {
    int rbase = m0 + (wm << 6) + (i << 4) + ((l >> 4) << 2);
#pragma unroll
    for (int j = 0; j < 4; ++j) {
      int col = n0 + (wn << 6) + (j << 4) + (l & 15);
      float bv = bias[col];
#pragma unroll
      for (int r = 0; r < 4; ++r) {
        int row = rbase + r;
        float v = acc[i][j][r] + bv;
        if (OUT == 2) {
          v = fmaxf(v, 0.f);
          Cb[(size_t)row * N + col] = f2bf(v);
        } else if (OUT == 1) {
          int b = row >> 11, ll = row & 2047, h = col >> 6, d = col & 63;
          Cf[((size_t)(((b << 3) + h) << 11) + ll) * 64 + d] = v;
        } else {
          Cf[(size_t)row * N + col] = v;
        }
      }
    }
  }
}

// ---------------------------------------------------------------------------
// Sampled-score M: 8 queries/wave, 8 lanes/query, line-contiguous loads.
// Each load instruction's 8-lane group covers exactly one 128B cache line
// per K row (vs 32 lines/instr before). XCD-affinity (bh = blockIdx&31)
// keeps each head's K panel L2-resident. 8192 waves = 32/CU for latency hide.
// ---------------------------------------------------------------------------
__global__ __launch_bounds__(256) void qk_m_kernel(
    const float* __restrict__ Q, const float* __restrict__ K,
    const int* __restrict__ sidx, float* __restrict__ Mout) {
  int t = threadIdx.x;
  int wave = t >> 6, lane = t & 63;
  int grp = lane >> 3, sub = lane & 7;          // 8 queries/wave, 8 lanes/query
  int bh = blockIdx.x & 31;
  int j = blockIdx.x >> 5;
  int item = (bh << 11) + (j << 5) + wave * 8 + grp;
  int l = item & 2047;
  // interleaved fragment: floats [sub*4..+3] and [32+sub*4..+3]
  const float* Qr = Q + (size_t)item * 64;
  float4 q0 = *(const float4*)(Qr + sub * 4);
  float4 q1 = *(const float4*)(Qr + 32 + sub * 4);
  const float* Kb = K + (((size_t)bh << 11) << 6);
  const int* sp = sidx + l * U_;
  float mx = -INFINITY, sm = 0.f;
#pragma unroll 8
  for (int u = 0; u < U_; ++u) {
    int kidx = sp[u];
    const float* kr = Kb + ((size_t)kidx << 6);
    float4 k0 = *(const float4*)(kr + sub * 4);
    float4 k1 = *(const float4*)(kr + 32 + sub * 4);
    float p = q0.x * k0.x + q0.y * k0.y + q0.z * k0.z + q0.w * k0.w;
    p = fmaf(q1.x, k1.x, p); p = fmaf(q1.y, k1.y, p);
    p = fmaf(q1.z, k1.z, p); p = fmaf(q1.w, k1.w, p);
    p += __shfl_xor(p, 1);
    p += __shfl_xor(p, 2);
    p += __shfl_xor(p, 4);
    mx = fmaxf(mx, p);
    sm += p;
  }
  if (sub == 0) Mout[item] = mx - sm * (1.0f / U_);
}

// ---------------------------------------------------------------------------
// Exact top-40 via 4-pass radix select — fully parallel (no serial tails).
// ---------------------------------------------------------------------------
__global__ __launch_bounds__(256) void topk_kernel(
    const float* __restrict__ Mb, int* __restrict__ TOP) {
  __shared__ unsigned vals[2048];
  __shared__ int hist[256];
  __shared__ int suf[256];
  __shared__ unsigned s_prefix;
  __shared__ int s_want, s_cnt, s_run;
  __shared__ int wcnt[4];
  int bh = blockIdx.x, t = threadIdx.x;
  int lane = t & 63, w = t >> 6;
  for (int i = t; i < 2048; i += 256) {
    unsigned u = __float_as_uint(Mb[bh * 2048 + i]);
    vals[i] = (u & 0x80000000u) ? ~u : (u | 0x80000000u);
  }
  if (t == 0) { s_prefix = 0; s_want = U_; s_cnt = 0; s_run = 0; }
  __syncthreads();
#pragma unroll
  for (int shift = 24; shift >= 0; shift -= 8) {
    unsigned pref = s_prefix;
    int want = s_want;
    unsigned hmask = (shift == 24) ? 0u : (0xFFFFFFFFu << (shift + 8));
    hist[t] = 0;
    __syncthreads();
    for (int i = t; i < 2048; i += 256) {
      unsigned v = vals[i];
      if ((v & hmask) == pref) atomicAdd(&hist[(v >> shift) & 255], 1);
    }
    __syncthreads();
    suf[t] = hist[t];
    __syncthreads();
    for (int off = 1; off < 256; off <<= 1) {
      int add = (t + off < 256) ? suf[t + off] : 0;
      __syncthreads();
      suf[t] += add;
      __syncthreads();
    }
    int cgt = (t == 255) ? 0 : suf[t + 1];
    if (suf[t] >= want && cgt < want) {
      s_prefix = pref | ((unsigned)t << shift);
      s_want = want - cgt;
    }
    __syncthreads();
  }
  unsigned T = s_prefix;
  int want_eq = s_want;
  int base = U_ - want_eq;
  for (int i = t; i < 2048; i += 256) {
    if (vals[i] > T) {
      int slot = atomicAdd(&s_cnt, 1);
      TOP[bh * U_ + slot] = i;
    }
  }
  for (int c = 0; c < 8; ++c) {
    int i = (c << 8) + t;
    bool eq = (vals[i] == T);
    unsigned long long m = __ballot(eq);
    if (lane == 0) wcnt[w] = __popcll(m);
    __syncthreads();
    int woff = 0;
    for (int ww = 0; ww < w; ++ww) woff += wcnt[ww];
    if (eq) {
      int rank = s_run + woff + __popcll(m & ((1ull << lane) - 1ull));
      if (rank < want_eq) TOP[bh * U_ + base + rank] = i;
    }
    __syncthreads();
    if (t == 0) s_run += wcnt[0] + wcnt[1] + wcnt[2] + wcnt[3];
    __syncthreads();
  }
}

// ---------------------------------------------------------------------------
// vmean[bh,d] = mean over L of V[bh,l,d]; also bf16 copy for ctxfill.
// ---------------------------------------------------------------------------
__global__ __launch_bounds__(256) void vmean_kernel(
    const float* __restrict__ V, float* __restrict__ VM,
    unsigned short* __restrict__ VMbf) {
  __shared__ float p[4][64];
  int bh = blockIdx.x;
  int d = threadIdx.x & 63, c = threadIdx.x >> 6;
  const float* Vb = V + (((size_t)bh << 11) + c * 512) * 64;
  float s = 0.f;
  for (int l = 0; l < 512; ++l) s += Vb[l * 64 + d];
  p[c][d] = s;
  __syncthreads();
  if (threadIdx.x < 64) {
    float m = (p[0][d] + p[1][d] + p[2][d] + p[3][d]) * (1.0f / 2048.0f);
    VM[bh * 64 + d] = m;
    VMbf[bh * 64 + d] = f2bf(m);
  }
}

// ---------------------------------------------------------------------------
// S[bh,u,k] = scale * dot(Q[top[bh,u]], K[bh,k]).
// ---------------------------------------------------------------------------
__global__ __launch_bounds__(256) void attn_score(
    const float* __restrict__ Q, const float* __restrict__ K,
    const int* __restrict__ TOP, float* __restrict__ S) {
  __shared__ float Ks[128 * 65];
  __shared__ float Qs[40 * 64];
  int bh = blockIdx.y, k0 = blockIdx.x << 7;
  int t = threadIdx.x;
  for (int i = t; i < 2560; i += 256) {
    int u = i >> 6, d = i & 63;
    int row = TOP[bh * U_ + u];
    Qs[i] = Q[(((size_t)bh << 11) + row) * 64 + d];
  }
  for (int i = t; i < 8192; i += 256) {
    int k = i >> 6, d = i & 63;
    Ks[k * 65 + d] = K[(((size_t)bh << 11) + k0 + k) * 64 + d];
  }
  __syncthreads();
  int kk = t & 127, ug = (t >> 7) * 20;
  const float* kp = Ks + kk * 65;
  for (int u = ug; u < ug + 20; ++u) {
    const float* qp = Qs + u * 64;
    float s = 0.f;
#pragma unroll 8
    for (int d = 0; d < 64; ++d) s = fmaf(qp[d], kp[d], s);
    S[((size_t)bh * U_ + u) * 2048 + k0 + kk] = s * SCALE_;
  }
}

// ---------------------------------------------------------------------------
// softmax + P@V for 8 query-rows per block; V chunk staged once in LDS.
// Writes scattered bf16 rows DIRECTLY into CTX (fused scatter).
// ---------------------------------------------------------------------------
__global__ __launch_bounds__(256) void attn_pv(
    const float* __restrict__ S, const float* __restrict__ V,
    const int* __restrict__ TOP, unsigned short* __restrict__ CTX) {
  __shared__ float Vs[128][64];
  __shared__ float ps[8][128];
  __shared__ float mred[8], ired[8];
  int ug = blockIdx.x, bh = blockIdx.y;
  int t = threadIdx.x, lane = t & 63, w = t >> 6;
  int rowbase = bh * U_ + ug * 8;

  for (int rr = w; rr < 8; rr += 4) {
    const float* Sr = S + (size_t)(rowbase + rr) * 2048;
    float mx = -INFINITY;
    for (int j = 0; j < 32; ++j) mx = fmaxf(mx, Sr[j * 64 + lane]);
#pragma unroll
    for (int s = 32; s; s >>= 1) mx = fmaxf(mx, __shfl_xor(mx, s));
    float sm = 0.f;
    for (int j = 0; j < 32; ++j) sm += __expf(Sr[j * 64 + lane] - mx);
#pragma unroll
    for (int s = 32; s; s >>= 1) sm += __shfl_xor(sm, s);
    if (lane == 0) { mred[rr] = mx; ired[rr] = 1.0f / sm; }
  }
  __syncthreads();

  const float* Vb = V + (((size_t)bh << 11) << 6);
  float acc0 = 0.f, acc1 = 0.f;
  for (int c = 0; c < 16; ++c) {
    int k0 = c << 7;
#pragma unroll
    for (int i = 0; i < 8; ++i) {
      int ve = t + i * 256;
      int k = ve >> 4, dq = ve & 15;
      *(float4*)&Vs[k][dq << 2] = *(const float4*)(Vb + (size_t)(k0 + k) * 64 + (dq << 2));
    }
#pragma unroll
    for (int i = 0; i < 4; ++i) {
      int e = t + i * 256;
      int r = e >> 7, kk = e & 127;
      ps[r][kk] = __expf(S[(size_t)(rowbase + r) * 2048 + k0 + kk] - mred[r]);
    }
    __syncthreads();
    const float* p0 = ps[w];
    const float* p1 = ps[w + 4];
    for (int kk = 0; kk < 128; ++kk) {
      float vv = Vs[kk][lane];
      acc0 = fmaf(p0[kk], vv, acc0);
      acc1 = fmaf(p1[kk], vv, acc1);
    }
    __syncthreads();
  }
  int b = bh >> 3, h = bh & 7;
  int row0 = TOP[rowbase + w];
  int row1 = TOP[rowbase + w + 4];
  CTX[((size_t)((b << 11) + row0) << 9) + (h << 6) + lane] = f2bf(acc0 * ired[w]);
  CTX[((size_t)((b << 11) + row1) << 9) + (h << 6) + lane] = f2bf(acc1 * ired[w + 4]);
}

// ---------------------------------------------------------------------------
// ctx fill (vectorized: 8 bf16 per thread; 2048 blocks x 256 x 8 = 4194304)
// ---------------------------------------------------------------------------
__global__ __launch_bounds__(256) void ctxfill_kernel(
    const unsigned short* __restrict__ VMbf, unsigned short* __restrict__ CTX) {
  int t8 = (blockIdx.x * 256 + threadIdx.x) << 3;
  int c0 = t8 & 511;
  int b = t8 >> 20;
  *(uint4*)(CTX + t8) = *(const uint4*)(VMbf + (b << 9) + c0);
}

// ---------------------------------------------------------------------------
// LayerNorm(512) with optional residual; float2-vectorized.
// ---------------------------------------------------------------------------
template <bool ADD, bool WB>
__global__ __launch_bounds__(256) void ln_kernel(
    const float* __restrict__ Xin, const float* __restrict__ Tin,
    const float* __restrict__ g, const float* __restrict__ bta,
    float* __restrict__ Xout, unsigned short* __restrict__ Xbf) {
  __shared__ float red[8];
  int r = blockIdx.x, t = threadIdx.x;
  int i0 = (r << 9) + (t << 1);
  float2 v = *(const float2*)(Xin + i0);
  if constexpr (ADD) {
    float2 tv = *(const float2*)(Tin + i0);
    v.x += tv.x; v.y += tv.y;
  }
  float sm = v.x + v.y;
#pragma unroll
  for (int s = 32; s; s >>= 1) sm += __shfl_xor(sm, s);
  int lane = t & 63, w = t >> 6;
  if (lane == 0) red[w] = sm;
  __syncthreads();
  float mean = (red[0] + red[1] + red[2] + red[3]) * (1.0f / 512.0f);
  float d0 = v.x - mean, d1 = v.y - mean;
  float sq = d0 * d0 + d1 * d1;
#pragma unroll
  for (int s = 32; s; s >>= 1) sq += __shfl_xor(sq, s);
  if (lane == 0) red[4 + w] = sq;
  __syncthreads();
  float var = (red[4] + red[5] + red[6] + red[7]) * (1.0f / 512.0f);
  float rstd = rsqrtf(var + EPS_);
  float2 gv = *(const float2*)(g + (t << 1));
  float2 bv = *(const float2*)(bta + (t << 1));
  float o0 = d0 * rstd * gv.x + bv.x;
  float o1 = d1 * rstd * gv.y + bv.y;
  *(float2*)(Xout + i0) = make_float2(o0, o1);
  if constexpr (WB) {
    *(unsigned*)(Xbf + i0) = (unsigned)f2bf(o0) | ((unsigned)f2bf(o1) << 16);
  }
}

// ---------------------------------------------------------------------------
// out = softmax(X @ W_out + b_out); one wave per row.
// ---------------------------------------------------------------------------
__global__ __launch_bounds__(256) void out_kernel(
    const float* __restrict__ X, const float* __restrict__ Wout,
    const float* __restrict__ bout, float* __restrict__ out) {
  int w = threadIdx.x >> 6, lane = threadIdx.x & 63;
  int r = blockIdx.x * 4 + w;
  float p0 = 0.f, p1 = 0.f, p2 = 0.f;
  for (int d = lane; d < 512; d += 64) {
    float x = X[(r << 9) + d];
    p0 += x * Wout[d * 3 + 0];
    p1 += x * Wout[d * 3 + 1];
    p2 += x * Wout[d * 3 + 2];
  }
#pragma unroll
  for (int s = 32; s; s >>= 1) {
    p0 += __shfl_xor(p0, s);
    p1 += __shfl_xor(p1, s);
    p2 += __shfl_xor(p2, s);
  }
  if (lane == 0) {
    p0 += bout[0]; p1 += bout[1]; p2 += bout[2];
    float m = fmaxf(p0, fmaxf(p1, p2));
    float e0 = __expf(p0 - m), e1 = __expf(p1 - m), e2 = __expf(p2 - m);
    float z = 1.0f / (e0 + e1 + e2);
    out[r * 3 + 0] = e0 * z;
    out[r * 3 + 1] = e1 * z;
    out[r * 3 + 2] = e2 * z;
  }
}

// ---------------------------------------------------------------------------
extern "C" void kernel_launch(void* const* d_in, const int* in_sizes, int n_in,
                              void* d_out, int out_size, void* d_ws, size_t ws_size,
                              hipStream_t stream) {
  const float* DNAs  = (const float*)d_in[0];
  const float* W_pre = (const float*)d_in[1];
  const float* b_pre = (const float*)d_in[2];
  const float* Wq    = (const float*)d_in[3];
  const float* bq    = (const float*)d_in[4];
  const float* Wk    = (const float*)d_in[5];
  const float* bk    = (const float*)d_in[6];
  const float* Wv    = (const float*)d_in[7];
  const float* bv    = (const float*)d_in[8];
  const float* Wo    = (const float*)d_in[9];
  const float* bo    = (const float*)d_in[10];
  const float* ln1_g = (const float*)d_in[11];
  const float* ln1_b = (const float*)d_in[12];
  const float* W1    = (const float*)d_in[13];
  const float* b1    = (const float*)d_in[14];
  const float* W2    = (const float*)d_in[15];
  const float* b2    = (const float*)d_in[16];
  const float* ln2_g = (const float*)d_in[17];
  const float* ln2_b = (const float*)d_in[18];
  const float* lnf_g = (const float*)d_in[19];
  const float* lnf_b = (const float*)d_in[20];
  const float* W_out = (const float*)d_in[21];
  const float* b_out = (const float*)d_in[22];
  const int*   sidx  = (const int*)d_in[23];
  float* out = (float*)d_out;

  float* ws = (float*)d_ws;
  float*          X     = ws;
  unsigned short* Xbf   = (unsigned short*)(ws + 4194304);
  float*          Qb    = ws + 6291456;
  float*          T     = Qb;
  float*          Kb    = ws + 10485760;
  float*          Vb    = ws + 14680064;
  float*          S     = ws + 18874368;
  unsigned short* CTXbf = (unsigned short*)(ws + 18874368 + 3276800);
  unsigned short* HBbf  = (unsigned short*)(ws + 18874368);
  unsigned short* WT    = (unsigned short*)(ws + 27262976);
  float*          Mb    = ws + 31981568;
  float*          VM    = ws + 32129024;
  int*            TOP   = (int*)(ws + 32131072);
  unsigned short* VMbf  = (unsigned short*)(ws + 32132352);
  unsigned short* WTqkvo = WT;
  unsigned short* WT1    = WT + 3145728;
  unsigned short* WT2    = WT + 6291456;
  (void)in_sizes; (void)n_in; (void)out_size; (void)ws_size;

  wtrans<<<dim3(16, 16, 12), 256, 0, stream>>>(Wq, Wk, Wv, Wo, WTqkvo, 512, 512, 262144);
  wtrans<<<dim3(64, 16, 3), 256, 0, stream>>>(W1, nullptr, nullptr, nullptr, WT1, 512, 2048, 1048576);
  wtrans<<<dim3(16, 64, 3), 256, 0, stream>>>(W2, nullptr, nullptr, nullptr, WT2, 2048, 512, 1048576);

  pre_kernel<<<16384, 256, 0, stream>>>(DNAs, W_pre, b_pre, X, Xbf);

  for (int i = 0; i < E_; ++i) {
    const int bOff = i * DM_;
    mgemm<1, true><<<dim3(4, 64, 3), 256, 0, stream>>>(
        Xbf, WTqkvo + (size_t)i * 262144, bq + bOff, bk + bOff, bv + bOff,
        Qb, nullptr, R_, DM_, DM_);

    qk_m_kernel<<<2048, 256, 0, stream>>>(Qb, Kb, sidx, Mb);
    topk_kernel<<<32, 256, 0, stream>>>(Mb, TOP);
    vmean_kernel<<<32, 256, 0, stream>>>(Vb, VM, VMbf);
    attn_score<<<dim3(16, 32), 256, 0, stream>>>(Qb, Kb, TOP, S);
    ctxfill_kernel<<<2048, 256, 0, stream>>>(VMbf, CTXbf);
    attn_pv<<<dim3(5, 32), 256, 0, stream>>>(S, Vb, TOP, CTXbf);

    mgemm<0, false><<<dim3(4, 64), 256, 0, stream>>>(
        CTXbf, WTqkvo + (size_t)(9 + i) * 262144, bo + bOff, nullptr, nullptr,
        T, nullptr, R_, DM_, DM_);
    ln_kernel<true, true><<<8192, 256, 0, stream>>>(X, T, ln1_g + bOff, ln1_b + bOff, X, Xbf);

    mgemm<2, false><<<dim3(16, 64), 256, 0, stream>>>(
        Xbf, WT1 + (size_t)i * 1048576, b1 + i * DFF_, nullptr, nullptr,
        nullptr, HBbf, R_, DFF_, DM_);
    mgemm<0, false><<<dim3(4, 64), 256, 0, stream>>>(
        HBbf, WT2 + (size_t)i * 1048576, b2 + bOff, nullptr, nullptr,
        T, nullptr, R_, DM_, DFF_);
    ln_kernel<true, true><<<8192, 256, 0, stream>>>(X, T, ln2_g + bOff, ln2_b + bOff, X, Xbf);
  }

  ln_kernel<false, false><<<8192, 256, 0, stream>>>(X, nullptr, lnf_g, lnf_b, X, nullptr);
  out_kernel<<<2048, 256, 0, stream>>>(X, W_out, b_out, out);
}

// Round 10
// 793.044 us; speedup vs baseline: 1.2554x; 1.0527x over previous
//
#include <hip/hip_runtime.h>
#include <math.h>

#define B_   4
#define L_   2048
#define DM_  512
#define H_   8
#define DK_  64
#define DFF_ 2048
#define E_   3
#define U_   40
#define R_   8192
#define SCALE_ 0.125f
#define EPS_ 1e-5f

typedef __bf16 bf16x8 __attribute__((ext_vector_type(8)));
typedef float f32x4 __attribute__((ext_vector_type(4)));

__device__ inline unsigned short f2bf(float x) {
  unsigned int u = __float_as_uint(x);
  unsigned int r = (u + 0x7fffu + ((u >> 16) & 1u)) >> 16;
  return (unsigned short)r;
}

// ---------------------------------------------------------------------------
// Weight transpose fp32 [R][C] -> bf16 [C][R].
// ---------------------------------------------------------------------------
__global__ __launch_bounds__(256) void wtrans(
    const float* __restrict__ s0, const float* __restrict__ s1,
    const float* __restrict__ s2, const float* __restrict__ s3,
    unsigned short* __restrict__ dst, int R, int C, int permat) {
  __shared__ float tile[32][33];
  int z = blockIdx.z;
  int which = z / 3, e = z % 3;
  const float* src = (which == 0 ? s0 : which == 1 ? s1 : which == 2 ? s2 : s3);
  src += (size_t)e * permat;
  unsigned short* d = dst + (size_t)z * permat;
  int c0 = blockIdx.x << 5, r0 = blockIdx.y << 5;
  int tx = threadIdx.x & 31, ty = threadIdx.x >> 5;
  for (int rr = ty; rr < 32; rr += 8)
    tile[rr][tx] = src[(size_t)(r0 + rr) * C + c0 + tx];
  __syncthreads();
  for (int cc = ty; cc < 32; cc += 8)
    d[(size_t)(c0 + cc) * R + r0 + tx] = f2bf(tile[tx][cc]);
}

// ---------------------------------------------------------------------------
// x = DNAs @ W_pre + b_pre ; writes fp32 X and bf16 Xbf
// ---------------------------------------------------------------------------
__global__ __launch_bounds__(256) void pre_kernel(
    const float* __restrict__ DNAs, const float* __restrict__ Wp,
    const float* __restrict__ bp, float* __restrict__ X,
    unsigned short* __restrict__ Xbf) {
  int t = blockIdx.x * 256 + threadIdx.x;
  int r = t >> 9, d = t & 511;
  float4 dna = *(const float4*)(DNAs + r * 4);
  float v = dna.x * Wp[d] + dna.y * Wp[512 + d] + dna.z * Wp[1024 + d] +
            dna.w * Wp[1536 + d] + bp[d];
  X[t] = v;
  Xbf[t] = f2bf(v);
}

// ---------------------------------------------------------------------------
// bf16 MFMA GEMM (m97 structure, 128x128 tile, BK=64, XOR-swizzled LDS).
// 1-D grid with XCD-affinity: my = id&63 -> id%8 == my%8, so all N-tiles of
// an M-row run on one XCD; A-panel + weights stay L2-resident (T1).
// M is always 8192 (64 M-tiles). OUT: 0 fp32 [M,N]; 1 fp32 QKV remap; 2 bf16+ReLU.
// ---------------------------------------------------------------------------
template <int OUT, bool QKVZ>
__global__ __launch_bounds__(256) void mgemm(
    const unsigned short* __restrict__ A, const unsigned short* __restrict__ BT,
    const float* __restrict__ bias0, const float* __restrict__ bias1,
    const float* __restrict__ bias2, float* __restrict__ Cf,
    unsigned short* __restrict__ Cb, int M, int N, int K) {
  __shared__ unsigned short As[128 * 64];
  __shared__ unsigned short Bs[128 * 64];
  const int t = threadIdx.x, l = t & 63, w = t >> 6;
  const int id = blockIdx.x;
  const int m0 = (id & 63) << 7, n0 = (id >> 6) << 7;
  const int wm = w >> 1, wn = w & 1;
  const float* bias = bias0;
  if (QKVZ) {
    int z = blockIdx.z;
    BT += (size_t)z * 3 * 262144;
    bias = (z == 0 ? bias0 : z == 1 ? bias1 : bias2);
    Cf += (size_t)z * 4194304;
  }
  f32x4 acc[4][4] = {};

  const int srow = l >> 3;
  const int gslot = (l & 7) ^ srow;
  for (int k0 = 0; k0 < K; k0 += 64) {
#pragma unroll
    for (int j = 0; j < 4; ++j) {
      int c = (w << 2) + j;
      int row = (c << 3) + srow;
      const unsigned short* ga = A + (size_t)(m0 + row) * K + k0 + gslot * 8;
      const unsigned short* gb = BT + (size_t)(n0 + row) * K + k0 + gslot * 8;
      __builtin_amdgcn_global_load_lds(
          (const __attribute__((address_space(1))) void*)ga,
          (__attribute__((address_space(3))) void*)(As + (c << 9)), 16, 0, 0);
      __builtin_amdgcn_global_load_lds(
          (const __attribute__((address_space(1))) void*)gb,
          (__attribute__((address_space(3))) void*)(Bs + (c << 9)), 16, 0, 0);
    }
    __syncthreads();
#pragma unroll
    for (int ks = 0; ks < 2; ++ks) {
      bf16x8 af[4], bg[4];
      int slot = (ks << 2) + (l >> 4);
#pragma unroll
      for (int i = 0; i < 4; ++i) {
        int ar = (wm << 6) + (i << 4) + (l & 15);
        af[i] = *(const bf16x8*)(As + ar * 64 + (slot ^ (ar & 7)) * 8);
        int br = (wn << 6) + (i << 4) + (l & 15);
        bg[i] = *(const bf16x8*)(Bs + br * 64 + (slot ^ (br & 7)) * 8);
      }
#pragma unroll
      for (int i = 0; i < 4; ++i)
#pragma unroll
        for (int j = 0; j < 4; ++j)
          acc[i][j] = __builtin_amdgcn_mfma_f32_16x16x32_bf16(af[i], bg[j],
                                                              acc[i][j], 0, 0, 0);
    }
    __syncthreads();
  }

#pragma unroll
  for (int i = 0; i < 4; ++i) {
    int rbase = m0 + (wm << 6) + (i << 4) + ((l >> 4) << 2);
#pragma unroll
    for (int j = 0; j < 4; ++j) {
      int col = n0 + (wn << 6) + (j << 4) + (l & 15);
      float bv = bias[col];
#pragma unroll
      for (int r = 0; r < 4; ++r) {
        int row = rbase + r;
        float v = acc[i][j][r] + bv;
        if (OUT == 2) {
          v = fmaxf(v, 0.f);
          Cb[(size_t)row * N + col] = f2bf(v);
        } else if (OUT == 1) {
          int b = row >> 11, ll = row & 2047, h = col >> 6, d = col & 63;
          Cf[((size_t)(((b << 3) + h) << 11) + ll) * 64 + d] = v;
        } else {
          Cf[(size_t)row * N + col] = v;
        }
      }
    }
  }
}

// ---------------------------------------------------------------------------
// Sampled-score M: 8 queries/wave, 8 lanes/query, line-contiguous loads.
// XCD-affinity (bh = blockIdx&31) keeps each head's K panel L2-resident.
// ---------------------------------------------------------------------------
__global__ __launch_bounds__(256) void qk_m_kernel(
    const float* __restrict__ Q, const float* __restrict__ K,
    const int* __restrict__ sidx, float* __restrict__ Mout) {
  int t = threadIdx.x;
  int wave = t >> 6, lane = t & 63;
  int grp = lane >> 3, sub = lane & 7;
  int bh = blockIdx.x & 31;
  int j = blockIdx.x >> 5;
  int item = (bh << 11) + (j << 5) + wave * 8 + grp;
  int l = item & 2047;
  const float* Qr = Q + (size_t)item * 64;
  float4 q0 = *(const float4*)(Qr + sub * 4);
  float4 q1 = *(const float4*)(Qr + 32 + sub * 4);
  const float* Kb = K + (((size_t)bh << 11) << 6);
  const int* sp = sidx + l * U_;
  float mx = -INFINITY, sm = 0.f;
#pragma unroll 8
  for (int u = 0; u < U_; ++u) {
    int kidx = sp[u];
    const float* kr = Kb + ((size_t)kidx << 6);
    float4 k0 = *(const float4*)(kr + sub * 4);
    float4 k1 = *(const float4*)(kr + 32 + sub * 4);
    float p = q0.x * k0.x + q0.y * k0.y + q0.z * k0.z + q0.w * k0.w;
    p = fmaf(q1.x, k1.x, p); p = fmaf(q1.y, k1.y, p);
    p = fmaf(q1.z, k1.z, p); p = fmaf(q1.w, k1.w, p);
    p += __shfl_xor(p, 1);
    p += __shfl_xor(p, 2);
    p += __shfl_xor(p, 4);
    mx = fmaxf(mx, p);
    sm += p;
  }
  if (sub == 0) Mout[item] = mx - sm * (1.0f / U_);
}

// ---------------------------------------------------------------------------
// Exact top-40 via 4-pass radix select — fully parallel (no serial tails).
// ---------------------------------------------------------------------------
__global__ __launch_bounds__(256) void topk_kernel(
    const float* __restrict__ Mb, int* __restrict__ TOP) {
  __shared__ unsigned vals[2048];
  __shared__ int hist[256];
  __shared__ int suf[256];
  __shared__ unsigned s_prefix;
  __shared__ int s_want, s_cnt, s_run;
  __shared__ int wcnt[4];
  int bh = blockIdx.x, t = threadIdx.x;
  int lane = t & 63, w = t >> 6;
  for (int i = t; i < 2048; i += 256) {
    unsigned u = __float_as_uint(Mb[bh * 2048 + i]);
    vals[i] = (u & 0x80000000u) ? ~u : (u | 0x80000000u);
  }
  if (t == 0) { s_prefix = 0; s_want = U_; s_cnt = 0; s_run = 0; }
  __syncthreads();
#pragma unroll
  for (int shift = 24; shift >= 0; shift -= 8) {
    unsigned pref = s_prefix;
    int want = s_want;
    unsigned hmask = (shift == 24) ? 0u : (0xFFFFFFFFu << (shift + 8));
    hist[t] = 0;
    __syncthreads();
    for (int i = t; i < 2048; i += 256) {
      unsigned v = vals[i];
      if ((v & hmask) == pref) atomicAdd(&hist[(v >> shift) & 255], 1);
    }
    __syncthreads();
    suf[t] = hist[t];
    __syncthreads();
    for (int off = 1; off < 256; off <<= 1) {
      int add = (t + off < 256) ? suf[t + off] : 0;
      __syncthreads();
      suf[t] += add;
      __syncthreads();
    }
    int cgt = (t == 255) ? 0 : suf[t + 1];
    if (suf[t] >= want && cgt < want) {
      s_prefix = pref | ((unsigned)t << shift);
      s_want = want - cgt;
    }
    __syncthreads();
  }
  unsigned T = s_prefix;
  int want_eq = s_want;
  int base = U_ - want_eq;
  for (int i = t; i < 2048; i += 256) {
    if (vals[i] > T) {
      int slot = atomicAdd(&s_cnt, 1);
      TOP[bh * U_ + slot] = i;
    }
  }
  for (int c = 0; c < 8; ++c) {
    int i = (c << 8) + t;
    bool eq = (vals[i] == T);
    unsigned long long m = __ballot(eq);
    if (lane == 0) wcnt[w] = __popcll(m);
    __syncthreads();
    int woff = 0;
    for (int ww = 0; ww < w; ++ww) woff += wcnt[ww];
    if (eq) {
      int rank = s_run + woff + __popcll(m & ((1ull << lane) - 1ull));
      if (rank < want_eq) TOP[bh * U_ + base + rank] = i;
    }
    __syncthreads();
    if (t == 0) s_run += wcnt[0] + wcnt[1] + wcnt[2] + wcnt[3];
    __syncthreads();
  }
}

// ---------------------------------------------------------------------------
// vmean[bh,d] = mean over L of V[bh,l,d]; also bf16 copy for ctxfill.
// ---------------------------------------------------------------------------
__global__ __launch_bounds__(256) void vmean_kernel(
    const float* __restrict__ V, float* __restrict__ VM,
    unsigned short* __restrict__ VMbf) {
  __shared__ float p[4][64];
  int bh = blockIdx.x;
  int d = threadIdx.x & 63, c = threadIdx.x >> 6;
  const float* Vb = V + (((size_t)bh << 11) + c * 512) * 64;
  float s = 0.f;
  for (int l = 0; l < 512; ++l) s += Vb[l * 64 + d];
  p[c][d] = s;
  __syncthreads();
  if (threadIdx.x < 64) {
    float m = (p[0][d] + p[1][d] + p[2][d] + p[3][d]) * (1.0f / 2048.0f);
    VM[bh * 64 + d] = m;
    VMbf[bh * 64 + d] = f2bf(m);
  }
}

// ---------------------------------------------------------------------------
// S[bh,u,k] = scale * dot(Q[top[bh,u]], K[bh,k]).
// ---------------------------------------------------------------------------
__global__ __launch_bounds__(256) void attn_score(
    const float* __restrict__ Q, const float* __restrict__ K,
    const int* __restrict__ TOP, float* __restrict__ S) {
  __shared__ float Ks[128 * 65];
  __shared__ float Qs[40 * 64];
  int bh = blockIdx.y, k0 = blockIdx.x << 7;
  int t = threadIdx.x;
  for (int i = t; i < 2560; i += 256) {
    int u = i >> 6, d = i & 63;
    int row = TOP[bh * U_ + u];
    Qs[i] = Q[(((size_t)bh << 11) + row) * 64 + d];
  }
  for (int i = t; i < 8192; i += 256) {
    int k = i >> 6, d = i & 63;
    Ks[k * 65 + d] = K[(((size_t)bh << 11) + k0 + k) * 64 + d];
  }
  __syncthreads();
  int kk = t & 127, ug = (t >> 7) * 20;
  const float* kp = Ks + kk * 65;
  for (int u = ug; u < ug + 20; ++u) {
    const float* qp = Qs + u * 64;
    float s = 0.f;
#pragma unroll 8
    for (int d = 0; d < 64; ++d) s = fmaf(qp[d], kp[d], s);
    S[((size_t)bh * U_ + u) * 2048 + k0 + kk] = s * SCALE_;
  }
}

// ---------------------------------------------------------------------------
// softmax + P@V: 512 threads, 8 waves, ONE ROW PER WAVE. Linear grid 160,
// bh = id&31 XCD-affinity (V L2-resident). Fused bf16 scatter into CTX.
// ---------------------------------------------------------------------------
__global__ __launch_bounds__(512) void attn_pv(
    const float* __restrict__ S, const float* __restrict__ V,
    const int* __restrict__ TOP, unsigned short* __restrict__ CTX) {
  __shared__ float Vs[128][64];
  __shared__ float ps[8][128];
  __shared__ float mred[8], ired[8];
  int id = blockIdx.x;
  int bh = id & 31, ug = id >> 5;
  int t = threadIdx.x, lane = t & 63, w = t >> 6;   // w in [0,8)
  int rowbase = bh * U_ + ug * 8;
  int row = rowbase + w;

  // phase 1: this wave's row max & inverse exp-sum
  const float* Sr = S + (size_t)row * 2048;
  float mx = -INFINITY;
  for (int j = 0; j < 32; ++j) mx = fmaxf(mx, Sr[j * 64 + lane]);
#pragma unroll
  for (int s = 32; s; s >>= 1) mx = fmaxf(mx, __shfl_xor(mx, s));
  float sm = 0.f;
  for (int j = 0; j < 32; ++j) sm += __expf(Sr[j * 64 + lane] - mx);
#pragma unroll
  for (int s = 32; s; s >>= 1) sm += __shfl_xor(sm, s);
  if (lane == 0) { mred[w] = mx; ired[w] = 1.0f / sm; }
  __syncthreads();

  const float* Vb = V + (((size_t)bh << 11) << 6);
  float acc = 0.f;
  for (int c = 0; c < 16; ++c) {
    int k0 = c << 7;
    // stage V chunk: 8192 floats / 512 threads = 4 x float4
#pragma unroll
    for (int i = 0; i < 4; ++i) {
      int ve = t + i * 512;
      int k = ve >> 4, dq = ve & 15;
      *(float4*)&Vs[k][dq << 2] = *(const float4*)(Vb + (size_t)(k0 + k) * 64 + (dq << 2));
    }
    // stage exp(S - m): 1024 / 512 = 2 each
#pragma unroll
    for (int i = 0; i < 2; ++i) {
      int e = t + i * 512;
      int r = e >> 7, kk = e & 127;
      ps[r][kk] = __expf(S[(size_t)(rowbase + r) * 2048 + k0 + kk] - mred[r]);
    }
    __syncthreads();
    const float* p = ps[w];
#pragma unroll 4
    for (int kk = 0; kk < 128; kk += 4) {
      float4 p4 = *(const float4*)(p + kk);
      acc = fmaf(p4.x, Vs[kk + 0][lane], acc);
      acc = fmaf(p4.y, Vs[kk + 1][lane], acc);
      acc = fmaf(p4.z, Vs[kk + 2][lane], acc);
      acc = fmaf(p4.w, Vs[kk + 3][lane], acc);
    }
    __syncthreads();
  }
  int b = bh >> 3, h = bh & 7;
  int orow = TOP[row];
  CTX[((size_t)((b << 11) + orow) << 9) + (h << 6) + lane] = f2bf(acc * ired[w]);
}

// ---------------------------------------------------------------------------
// ctx fill (vectorized: 8 bf16 per thread; 2048 blocks x 256 x 8 = 4194304)
// ---------------------------------------------------------------------------
__global__ __launch_bounds__(256) void ctxfill_kernel(
    const unsigned short* __restrict__ VMbf, unsigned short* __restrict__ CTX) {
  int t8 = (blockIdx.x * 256 + threadIdx.x) << 3;
  int c0 = t8 & 511;
  int b = t8 >> 20;
  *(uint4*)(CTX + t8) = *(const uint4*)(VMbf + (b << 9) + c0);
}

// ---------------------------------------------------------------------------
// LayerNorm(512) with optional residual; float2-vectorized.
// ---------------------------------------------------------------------------
template <bool ADD, bool WB>
__global__ __launch_bounds__(256) void ln_kernel(
    const float* __restrict__ Xin, const float* __restrict__ Tin,
    const float* __restrict__ g, const float* __restrict__ bta,
    float* __restrict__ Xout, unsigned short* __restrict__ Xbf) {
  __shared__ float red[8];
  int r = blockIdx.x, t = threadIdx.x;
  int i0 = (r << 9) + (t << 1);
  float2 v = *(const float2*)(Xin + i0);
  if constexpr (ADD) {
    float2 tv = *(const float2*)(Tin + i0);
    v.x += tv.x; v.y += tv.y;
  }
  float sm = v.x + v.y;
#pragma unroll
  for (int s = 32; s; s >>= 1) sm += __shfl_xor(sm, s);
  int lane = t & 63, w = t >> 6;
  if (lane == 0) red[w] = sm;
  __syncthreads();
  float mean = (red[0] + red[1] + red[2] + red[3]) * (1.0f / 512.0f);
  float d0 = v.x - mean, d1 = v.y - mean;
  float sq = d0 * d0 + d1 * d1;
#pragma unroll
  for (int s = 32; s; s >>= 1) sq += __shfl_xor(sq, s);
  if (lane == 0) red[4 + w] = sq;
  __syncthreads();
  float var = (red[4] + red[5] + red[6] + red[7]) * (1.0f / 512.0f);
  float rstd = rsqrtf(var + EPS_);
  float2 gv = *(const float2*)(g + (t << 1));
  float2 bv = *(const float2*)(bta + (t << 1));
  float o0 = d0 * rstd * gv.x + bv.x;
  float o1 = d1 * rstd * gv.y + bv.y;
  *(float2*)(Xout + i0) = make_float2(o0, o1);
  if constexpr (WB) {
    *(unsigned*)(Xbf + i0) = (unsigned)f2bf(o0) | ((unsigned)f2bf(o1) << 16);
  }
}

// ---------------------------------------------------------------------------
// out = softmax(X @ W_out + b_out); one wave per row.
// ---------------------------------------------------------------------------
__global__ __launch_bounds__(256) void out_kernel(
    const float* __restrict__ X, const float* __restrict__ Wout,
    const float* __restrict__ bout, float* __restrict__ out) {
  int w = threadIdx.x >> 6, lane = threadIdx.x & 63;
  int r = blockIdx.x * 4 + w;
  float p0 = 0.f, p1 = 0.f, p2 = 0.f;
  for (int d = lane; d < 512; d += 64) {
    float x = X[(r << 9) + d];
    p0 += x * Wout[d * 3 + 0];
    p1 += x * Wout[d * 3 + 1];
    p2 += x * Wout[d * 3 + 2];
  }
#pragma unroll
  for (int s = 32; s; s >>= 1) {
    p0 += __shfl_xor(p0, s);
    p1 += __shfl_xor(p1, s);
    p2 += __shfl_xor(p2, s);
  }
  if (lane == 0) {
    p0 += bout[0]; p1 += bout[1]; p2 += bout[2];
    float m = fmaxf(p0, fmaxf(p1, p2));
    float e0 = __expf(p0 - m), e1 = __expf(p1 - m), e2 = __expf(p2 - m);
    float z = 1.0f / (e0 + e1 + e2);
    out[r * 3 + 0] = e0 * z;
    out[r * 3 + 1] = e1 * z;
    out[r * 3 + 2] = e2 * z;
  }
}

// ---------------------------------------------------------------------------
extern "C" void kernel_launch(void* const* d_in, const int* in_sizes, int n_in,
                              void* d_out, int out_size, void* d_ws, size_t ws_size,
                              hipStream_t stream) {
  const float* DNAs  = (const float*)d_in[0];
  const float* W_pre = (const float*)d_in[1];
  const float* b_pre = (const float*)d_in[2];
  const float* Wq    = (const float*)d_in[3];
  const float* bq    = (const float*)d_in[4];
  const float* Wk    = (const float*)d_in[5];
  const float* bk    = (const float*)d_in[6];
  const float* Wv    = (const float*)d_in[7];
  const float* bv    = (const float*)d_in[8];
  const float* Wo    = (const float*)d_in[9];
  const float* bo    = (const float*)d_in[10];
  const float* ln1_g = (const float*)d_in[11];
  const float* ln1_b = (const float*)d_in[12];
  const float* W1    = (const float*)d_in[13];
  const float* b1    = (const float*)d_in[14];
  const float* W2    = (const float*)d_in[15];
  const float* b2    = (const float*)d_in[16];
  const float* ln2_g = (const float*)d_in[17];
  const float* ln2_b = (const float*)d_in[18];
  const float* lnf_g = (const float*)d_in[19];
  const float* lnf_b = (const float*)d_in[20];
  const float* W_out = (const float*)d_in[21];
  const float* b_out = (const float*)d_in[22];
  const int*   sidx  = (const int*)d_in[23];
  float* out = (float*)d_out;

  float* ws = (float*)d_ws;
  float*          X     = ws;
  unsigned short* Xbf   = (unsigned short*)(ws + 4194304);
  float*          Qb    = ws + 6291456;
  float*          T     = Qb;
  float*          Kb    = ws + 10485760;
  float*          Vb    = ws + 14680064;
  float*          S     = ws + 18874368;
  unsigned short* CTXbf = (unsigned short*)(ws + 18874368 + 3276800);
  unsigned short* HBbf  = (unsigned short*)(ws + 18874368);
  unsigned short* WT    = (unsigned short*)(ws + 27262976);
  float*          Mb    = ws + 31981568;
  float*          VM    = ws + 32129024;
  int*            TOP   = (int*)(ws + 32131072);
  unsigned short* VMbf  = (unsigned short*)(ws + 32132352);
  unsigned short* WTqkvo = WT;
  unsigned short* WT1    = WT + 3145728;
  unsigned short* WT2    = WT + 6291456;
  (void)in_sizes; (void)n_in; (void)out_size; (void)ws_size;

  wtrans<<<dim3(16, 16, 12), 256, 0, stream>>>(Wq, Wk, Wv, Wo, WTqkvo, 512, 512, 262144);
  wtrans<<<dim3(64, 16, 3), 256, 0, stream>>>(W1, nullptr, nullptr, nullptr, WT1, 512, 2048, 1048576);
  wtrans<<<dim3(16, 64, 3), 256, 0, stream>>>(W2, nullptr, nullptr, nullptr, WT2, 2048, 512, 1048576);

  pre_kernel<<<16384, 256, 0, stream>>>(DNAs, W_pre, b_pre, X, Xbf);

  for (int i = 0; i < E_; ++i) {
    const int bOff = i * DM_;
    mgemm<1, true><<<dim3(256, 1, 3), 256, 0, stream>>>(
        Xbf, WTqkvo + (size_t)i * 262144, bq + bOff, bk + bOff, bv + bOff,
        Qb, nullptr, R_, DM_, DM_);

    qk_m_kernel<<<2048, 256, 0, stream>>>(Qb, Kb, sidx, Mb);
    topk_kernel<<<32, 256, 0, stream>>>(Mb, TOP);
    vmean_kernel<<<32, 256, 0, stream>>>(Vb, VM, VMbf);
    attn_score<<<dim3(16, 32), 256, 0, stream>>>(Qb, Kb, TOP, S);
    ctxfill_kernel<<<2048, 256, 0, stream>>>(VMbf, CTXbf);
    attn_pv<<<160, 512, 0, stream>>>(S, Vb, TOP, CTXbf);

    mgemm<0, false><<<256, 256, 0, stream>>>(
        CTXbf, WTqkvo + (size_t)(9 + i) * 262144, bo + bOff, nullptr, nullptr,
        T, nullptr, R_, DM_, DM_);
    ln_kernel<true, true><<<8192, 256, 0, stream>>>(X, T, ln1_g + bOff, ln1_b + bOff, X, Xbf);

    mgemm<2, false><<<1024, 256, 0, stream>>>(
        Xbf, WT1 + (size_t)i * 1048576, b1 + i * DFF_, nullptr, nullptr,
        nullptr, HBbf, R_, DFF_, DM_);
    mgemm<0, false><<<256, 256, 0, stream>>>(
        HBbf, WT2 + (size_t)i * 1048576, b2 + bOff, nullptr, nullptr,
        T, nullptr, R_, DM_, DFF_);
    ln_kernel<true, true><<<8192, 256, 0, stream>>>(X, T, ln2_g + bOff, ln2_b + bOff, X, Xbf);
  }

  ln_kernel<false, false><<<8192, 256, 0, stream>>>(X, nullptr, lnf_g, lnf_b, X, nullptr);
  out_kernel<<<2048, 256, 0, stream>>>(X, W_out, b_out, out);
}